// Round 4
// baseline (448.264 us; speedup 1.0000x reference)
//
#include <hip/hip_runtime.h>
#include <math.h>

// Problem constants
#define BB   2
#define LL   1024
#define HH   768
#define NHH  12
#define NEE  24
#define MMM  3
#define NCC  2
#define CWW  8
#define BLK  64
#define NCLS 97
#define HB   49152       // HH*BLK
#define NCP  128         // padded class dim for Wf
#define NCT  7           // class tiles computed (112 >= 97)
#define NEF  1152        // BB*NEE*NEE

typedef unsigned int uint;
typedef unsigned short ushort;
typedef __attribute__((ext_vector_type(8))) short bf16x8;
typedef __attribute__((ext_vector_type(4))) float f32x4;

// round-to-nearest-even fp32 -> bf16
__device__ __forceinline__ ushort f2bf(float f) {
    uint u = __float_as_uint(f);
    u += 0x7fffu + ((u >> 16) & 1u);
    return (ushort)(u >> 16);
}

// split fp32 into hi+lo bf16 (hi RNE, lo = RNE(f - hi)): ~16-bit mantissa total
__device__ __forceinline__ void splitbf(float f, ushort& h, ushort& l) {
    h = f2bf(f);
    float hf = __uint_as_float((uint)h << 16);
    l = f2bf(f - hf);
}

// ---------------------------------------------------------------------------
// K0 k_front: all input-only preprocessing in one launch.
//   [0,42):      wcpack (W_cls -> bf16 B-fragments)
//   [42,479):    out init with b_cls
//   [479,527):   head: e_att + gate + e_emb per (b,e)      (53KB LDS)
//   [527,911):   seq^T split-transpose -> seqThi/seqTlo [b][d][l]
//   [911,1295):  W2 split pack -> W2hi/W2lo [n][k] (cols 768: of Wh/Wt)
__global__ void k_front(const float* __restrict__ att_in, const float* __restrict__ seq,
                        const int* __restrict__ ms, const int* __restrict__ cs,
                        const float* __restrict__ Wc, const float* __restrict__ Wh,
                        const float* __restrict__ Wt, const float* __restrict__ bc,
                        float* __restrict__ e_att, float* __restrict__ e_emb,
                        ushort* __restrict__ wcpack,
                        ushort* __restrict__ seqThi, ushort* __restrict__ seqTlo,
                        ushort* __restrict__ W2hi, ushort* __restrict__ W2lo,
                        float* __restrict__ out) {
    __shared__ float sm[13328];     // head: es[12*1024]+gs[1024]+red[16]; transpose: 64x65
    int bid = blockIdx.x;
    int tid = threadIdx.x;
    if (bid < 42) {
        int t = bid * 256 + tid;
        if (t >= 24 * NCT * 64) return;
        int kc = t / (NCT * 64);
        int r = t % (NCT * 64);
        int ct = r >> 6;
        int lane = r & 63;
        int c = ct * 16 + (lane & 15);
        int k0 = kc * 32 + (lane >> 4) * 8;
        uint u[4] = {0u, 0u, 0u, 0u};
        if (c < NCLS) {
            const float* src = Wc + (size_t)c * HH + k0;
            float4 f0 = *(const float4*)src;
            float4 f1 = *(const float4*)(src + 4);
            u[0] = (uint)f2bf(f0.x) | ((uint)f2bf(f0.y) << 16);
            u[1] = (uint)f2bf(f0.z) | ((uint)f2bf(f0.w) << 16);
            u[2] = (uint)f2bf(f1.x) | ((uint)f2bf(f1.y) << 16);
            u[3] = (uint)f2bf(f1.z) | ((uint)f2bf(f1.w) << 16);
        }
        *(uint4*)(wcpack + (size_t)t * 8) = make_uint4(u[0], u[1], u[2], u[3]);
    } else if (bid < 479) {
        int i = (bid - 42) * 256 + tid;
        if (i < NEF * NCLS) out[i] = bc[i % NCLS];
    } else if (bid < 527) {
        // head: per (b,e)
        float* es = sm;                // 12*1024
        float* gs = sm + 12288;        // 1024
        float* red = sm + 13312;       // 4
        int be = bid - 479;
        int b = be / NEE;
        int base = be * MMM;
        int p0 = ms[base + 0] + 1, p1 = ms[base + 1] + 1, p2 = ms[base + 2] + 1;
        float* eo = e_att + (size_t)be * NHH * LL;
        for (int h = 0; h < NHH; h++) {
            const float* basep = att_in + (size_t)(b * NHH + h) * LL * LL;
#pragma unroll
            for (int i = 0; i < 4; i++) {
                int l = tid + i * 256;
                float v = (basep[(size_t)p0 * LL + l] + basep[(size_t)p1 * LL + l] +
                           basep[(size_t)p2 * LL + l]) * (1.f / 3.f);
                es[h * LL + l] = v;
                eo[h * LL + l] = v;
            }
        }
        __syncthreads();
        float part = 0.f;
#pragma unroll
        for (int i = 0; i < 4; i++) {
            int l = tid + i * 256;
            float a = 0.f;
#pragma unroll
            for (int h = 0; h < NHH; h++) a += es[h * LL + l];
            gs[l] = a;
            part += a;
        }
        for (int off = 32; off; off >>= 1) part += __shfl_down(part, off, 64);
        if ((tid & 63) == 0) red[tid >> 6] = part;
        __syncthreads();
        float inv = 1.f / (red[0] + red[1] + red[2] + red[3]);
#pragma unroll
        for (int i = 0; i < 4; i++) gs[tid + i * 256] *= inv;
        __syncthreads();
        int c0 = cs[be * NCC + 0], c1 = cs[be * NCC + 1];
        for (int d = tid; d < HH; d += 256) {
            float v0 = seq[((size_t)b * LL + p0) * HH + d];
            float v1 = seq[((size_t)b * LL + p1) * HH + d];
            float v2 = seq[((size_t)b * LL + p2) * HH + d];
            float s0 = 0.f, s1 = 0.f;
#pragma unroll
            for (int w = 0; w < CWW; w++) {
                s0 += gs[c0 + w] * seq[((size_t)b * LL + c0 + w) * HH + d];
                s1 += gs[c1 + w] * seq[((size_t)b * LL + c1 + w) * HH + d];
            }
            float mx = fmaxf(fmaxf(fmaxf(v0, v1), fmaxf(v2, s0)), s1);
            float se = expf(v0 - mx) + expf(v1 - mx) + expf(v2 - mx) + expf(s0 - mx) + expf(s1 - mx);
            e_emb[(size_t)be * HH + d] = logf(se) + mx;
        }
    } else if (bid < 911) {
        // seq^T split-transpose: 64(l) x 64(d) tiles
        float (*tile)[65] = (float(*)[65])sm;
        int idx = bid - 527;
        int b = idx / 192;
        int rem = idx % 192;
        int l0 = (rem / 12) * 64;
        int d0 = (rem % 12) * 64;
        int dq = tid >> 6, dl = tid & 63;
#pragma unroll 4
        for (int r = 0; r < 16; r++) {
            int l_in = r * 4 + dq;
            tile[l_in][dl] = seq[((size_t)(b * LL + l0 + l_in)) * HH + d0 + dl];
        }
        __syncthreads();
#pragma unroll 4
        for (int r = 0; r < 16; r++) {
            int d_out = r * 4 + dq;
            float v = tile[dl][d_out];
            ushort h, l;
            splitbf(v, h, l);
            size_t o = ((size_t)(b * HH + d0 + d_out)) * LL + l0 + dl;
            seqThi[o] = h;
            seqTlo[o] = l;
        }
    } else {
        // W2 split pack: W2[n][k] = (n<768 ? Wh : Wt)[n%768][768+k]
        int idx = bid - 911;
#pragma unroll
        for (int rr = 0; rr < 4; rr++) {
            int n = idx * 4 + rr;
            const float* src = (n < HH) ? (Wh + (size_t)n * (2 * HH) + HH)
                                        : (Wt + (size_t)(n - HH) * (2 * HH) + HH);
            for (int k = tid; k < HH; k += 256) {
                ushort h, l;
                splitbf(src[k], h, l);
                W2hi[(size_t)n * HH + k] = h;
                W2lo[(size_t)n * HH + k] = l;
            }
        }
    }
}

// ---------------------------------------------------------------------------
// K1 k_htwf: co-scheduled independent jobs.
//   [0,768):     wf  — bf16 MFMA GEMM Wf[n,c]; W_proj staged via global_load_lds
//                (coalesced 16B/lane, was 8x scattered dword = 256B/wave/inst)
//   [768,1920):  ht  — relu+normalize, emitted pre-split as hthi/htlo
__global__ void k_htwf(const float* __restrict__ e_att, const float* __restrict__ Wp,
                       const ushort* __restrict__ wcpack, ushort* __restrict__ hthi,
                       ushort* __restrict__ htlo, ushort* __restrict__ bpack) {
    __shared__ float smem[2052];    // wf: 32x64 Wp tile (8KB); ht: hts[1024]+red[4]
    int bid = blockIdx.x;
    int tid = threadIdx.x;
    int lane = tid & 63, w = tid >> 6;
    if (bid < 768) {
        int r16 = lane & 15, tt = lane >> 4;
        int n0 = bid * 64;
        const uint4* wb = (const uint4*)wcpack;
        f32x4 acc[NCT];
        f32x4 zero = {0.f, 0.f, 0.f, 0.f};
#pragma unroll
        for (int ct = 0; ct < NCT; ct++) acc[ct] = zero;
        for (int kc = 0; kc < 24; kc++) {
            // stage Wp[kc*32..+32][n0..n0+64] fp32 -> smem, linear [32][64]
#pragma unroll
            for (int q = 0; q < 2; q++) {
                int base = q * 256 + w * 64;          // wave-uniform slot base
                int srow = (base + lane) >> 4;
                int scol = ((base + lane) & 15) * 4;
                __builtin_amdgcn_global_load_lds(
                    (const __attribute__((address_space(1))) void*)
                        (Wp + (size_t)(kc * 32 + srow) * HB + n0 + scol),
                    (__attribute__((address_space(3))) void*)((char*)smem + base * 16),
                    16, 0, 0);
            }
            __syncthreads();
            float f[8];
#pragma unroll
            for (int j = 0; j < 8; j++) f[j] = smem[(tt * 8 + j) * 64 + w * 16 + r16];
            union { bf16x8 v; uint u[4]; } a;
#pragma unroll
            for (int q = 0; q < 4; q++)
                a.u[q] = (__float_as_uint(f[2 * q]) >> 16) |
                         (__float_as_uint(f[2 * q + 1]) & 0xFFFF0000u);  // truncate pair
#pragma unroll
            for (int ct = 0; ct < NCT; ct++) {
                union { uint4 q; bf16x8 v; } b;
                b.q = wb[(size_t)(kc * NCT + ct) * 64 + lane];
                acc[ct] = __builtin_amdgcn_mfma_f32_16x16x32_bf16(a.v, b.v, acc[ct], 0, 0, 0);
            }
            __syncthreads();
        }
#pragma unroll
        for (int ct = 0; ct < NCT; ct++) {
            int c = ct * 16 + r16;
#pragma unroll
            for (int r = 0; r < 4; r++) {
                int n = n0 + w * 16 + tt * 4 + r;
                bpack[((size_t)(n >> 3) * NCP + c) * 8 + (n & 7)] = f2bf(acc[ct][r]);
            }
        }
    } else {
        float* hts = smem;
        float* red = smem + 1024;
        int blk = bid - 768;            // ((b*NEE+e)*NEE+f)
        int f = blk % NEE;
        int e = (blk / NEE) % NEE;
        int b = blk / (NEE * NEE);
        const float* ea = e_att + (size_t)(b * NEE + e) * NHH * LL;
        const float* fa = e_att + (size_t)(b * NEE + f) * NHH * LL;
        float lsum = 0.f;
        for (int l = tid; l < LL; l += 256) {
            float s = 0.f;
            for (int h = 0; h < NHH; h++) s += ea[h * LL + l] * fa[h * LL + l];
            s = fmaxf(s, 0.f);
            hts[l] = s;
            lsum += s;
        }
        for (int off = 32; off; off >>= 1) lsum += __shfl_down(lsum, off, 64);
        if ((tid & 63) == 0) red[tid >> 6] = lsum;
        __syncthreads();
        float inv = 1.f / (red[0] + red[1] + red[2] + red[3] + 1e-10f);
        for (int l = tid; l < LL; l += 256) {
            ushort h, lo;
            splitbf(hts[l] * inv, h, lo);
            hthi[(size_t)blk * LL + l] = h;
            htlo[(size_t)blk * LL + l] = lo;
        }
    }
}

// ---------------------------------------------------------------------------
// K2 k_mid (128 threads):
//   [0,432):      rs GEMM via split-bf16 MFMA, M-tile 32 x N-tile 64 (2 waves)
//                 — was 216 blocks (<256 CUs, latency-bound); now 432.
//   [432,2736):   hsW/tsW (e_emb @ first-768-cols of Wh/Wt), 32 d per block
__global__ void k_mid(const ushort* __restrict__ seqThi, const ushort* __restrict__ seqTlo,
                      const ushort* __restrict__ hthi, const ushort* __restrict__ htlo,
                      const float* __restrict__ e_emb, const float* __restrict__ Wh,
                      const float* __restrict__ Wt, ushort* __restrict__ rshi,
                      ushort* __restrict__ rslo, float* __restrict__ hsW,
                      float* __restrict__ tsW) {
    __shared__ float xs[HH];
    int bid = blockIdx.x;
    int tid = threadIdx.x;
    int lane = tid & 63, w = tid >> 6;      // w in 0..1
    if (bid < 432) {
        int b = bid / 216;
        int rem = bid % 216;
        int m0 = (rem / 12) * 32;
        int n0 = (rem % 12) * 64;
        int r16 = lane & 15, tt = lane >> 4;
        const ushort* Ah = hthi + (size_t)(b * 576 + m0 + w * 16 + r16) * LL;
        const ushort* Al = htlo + (size_t)(b * 576 + m0 + w * 16 + r16) * LL;
        const ushort* Bh0 = seqThi + (size_t)(b * HH + n0 + r16) * LL;
        const ushort* Bl0 = seqTlo + (size_t)(b * HH + n0 + r16) * LL;
        f32x4 acc[4];
        f32x4 zero = {0.f, 0.f, 0.f, 0.f};
#pragma unroll
        for (int nt = 0; nt < 4; nt++) acc[nt] = zero;
        for (int kc = 0; kc < 32; kc++) {
            int ko = kc * 32 + tt * 8;
            bf16x8 ah = *(const bf16x8*)(Ah + ko);
            bf16x8 al = *(const bf16x8*)(Al + ko);
#pragma unroll
            for (int nt = 0; nt < 4; nt++) {
                bf16x8 bh = *(const bf16x8*)(Bh0 + (size_t)nt * 16 * LL + ko);
                bf16x8 bl = *(const bf16x8*)(Bl0 + (size_t)nt * 16 * LL + ko);
                acc[nt] = __builtin_amdgcn_mfma_f32_16x16x32_bf16(ah, bh, acc[nt], 0, 0, 0);
                acc[nt] = __builtin_amdgcn_mfma_f32_16x16x32_bf16(ah, bl, acc[nt], 0, 0, 0);
                acc[nt] = __builtin_amdgcn_mfma_f32_16x16x32_bf16(al, bh, acc[nt], 0, 0, 0);
            }
        }
#pragma unroll
        for (int nt = 0; nt < 4; nt++) {
#pragma unroll
            for (int r = 0; r < 4; r++) {
                int m = b * 576 + m0 + w * 16 + tt * 4 + r;
                int d = n0 + nt * 16 + r16;
                ushort h, l;
                splitbf(acc[nt][r], h, l);
                rshi[(size_t)m * HH + d] = h;
                rslo[(size_t)m * HH + d] = l;
            }
        }
    } else {
        int r = bid - 432;                // 0..2303
        int m2 = r % 48;
        int which = (r / 48) & 1;
        int chunk = r / 96;               // 0..23 (32 d's each)
        const float* Wm = which ? Wt : Wh;
        float* outp = which ? tsW : hsW;
        const float* x = e_emb + (size_t)m2 * HH;
        for (int j = tid; j < HH; j += 128) xs[j] = x[j];
        __syncthreads();
        int d0 = chunk * 32 + w * 16;
#pragma unroll 4
        for (int i = 0; i < 16; i++) {
            int d = d0 + i;
            const float* wr = Wm + (size_t)d * (2 * HH);
            float s = 0.f;
#pragma unroll
            for (int jj = 0; jj < 12; jj++) s += xs[lane + jj * 64] * wr[lane + jj * 64];
            for (int off = 32; off; off >>= 1) s += __shfl_down(s, off, 64);
            if (lane == 0) outp[(size_t)m2 * HH + d] = s;
        }
    }
}

// ---------------------------------------------------------------------------
// K3 k_rsw: split-bf16 MFMA GEMM + tanh epilogue -> zb.
// zb[m,n] = bf16(tanh(sum_k rs[m,k]*W2[n,k] + hs/ts + bias)). M=1152,N=1536,K=768.
__global__ void k_rsw(const ushort* __restrict__ rshi, const ushort* __restrict__ rslo,
                      const ushort* __restrict__ W2hi, const ushort* __restrict__ W2lo,
                      const float* __restrict__ hsW, const float* __restrict__ tsW,
                      const float* __restrict__ bh, const float* __restrict__ bt,
                      ushort* __restrict__ zb) {
    int m0 = blockIdx.x * 64, n0 = blockIdx.y * 64;
    int tid = threadIdx.x;
    int lane = tid & 63, w = tid >> 6;
    int r16 = lane & 15, tt = lane >> 4;
    const ushort* Ah = rshi + (size_t)(m0 + w * 16 + r16) * HH;
    const ushort* Al = rslo + (size_t)(m0 + w * 16 + r16) * HH;
    const ushort* Bh0 = W2hi + (size_t)(n0 + r16) * HH;
    const ushort* Bl0 = W2lo + (size_t)(n0 + r16) * HH;
    f32x4 acc[4];
    f32x4 zero = {0.f, 0.f, 0.f, 0.f};
#pragma unroll
    for (int nt = 0; nt < 4; nt++) acc[nt] = zero;
    for (int kc = 0; kc < 24; kc++) {
        int ko = kc * 32 + tt * 8;
        bf16x8 ah = *(const bf16x8*)(Ah + ko);
        bf16x8 al = *(const bf16x8*)(Al + ko);
#pragma unroll
        for (int nt = 0; nt < 4; nt++) {
            bf16x8 vbh = *(const bf16x8*)(Bh0 + (size_t)nt * 16 * HH + ko);
            bf16x8 vbl = *(const bf16x8*)(Bl0 + (size_t)nt * 16 * HH + ko);
            acc[nt] = __builtin_amdgcn_mfma_f32_16x16x32_bf16(ah, vbh, acc[nt], 0, 0, 0);
            acc[nt] = __builtin_amdgcn_mfma_f32_16x16x32_bf16(ah, vbl, acc[nt], 0, 0, 0);
            acc[nt] = __builtin_amdgcn_mfma_f32_16x16x32_bf16(al, vbh, acc[nt], 0, 0, 0);
        }
    }
    bool isHead = (n0 < HH);
    const float* bias = isHead ? bh : bt;
#pragma unroll
    for (int nt = 0; nt < 4; nt++) {
#pragma unroll
        for (int r = 0; r < 4; r++) {
            int m = m0 + w * 16 + tt * 4 + r;
            int n = n0 + nt * 16 + r16;
            int bb = m / 576;
            int rr = m % 576;
            int e = rr / NEE, f = rr % NEE;
            int d = isHead ? n : (n - HH);
            const float* addrow = isHead ? (hsW + (size_t)(bb * NEE + e) * HH)
                                         : (tsW + (size_t)(bb * NEE + f) * HH);
            float v = tanhf(acc[nt][r] + addrow[d] + bias[d]);
            zb[(size_t)m * (2 * HH) + n] = f2bf(v);
        }
    }
}

// ---------------------------------------------------------------------------
// K4 k_logits: MFMA logits. out[m,c] += bl[m,k]*Wf[c,k], bl built on the fly.
// zt/zh kept as FP32 in LDS: zt in XOR-swizzled 16B slots (conflict-free b128),
// zh at stride 33 (conflict-free scalar); products packed via v_cvt_pk_bf16_f32.
// Replaces the old bf16 bit-twiddle path (28 VALU + a 16-way-conflicted
// ds_read_u16 per fragment).
__global__ __launch_bounds__(256, 2) void k_logits(const ushort* __restrict__ zb,
                                                   const ushort* __restrict__ bpack,
                                                   float* __restrict__ out) {
    __shared__ float zhs_f[64 * 33];    // 8.25KB
    __shared__ float zts_f[64 * 64];    // 16KB, 16B slots XORed by ((row&7)<<4)
    __shared__ ushort Bls[16384];       // 32KB: one K=128 stage of B-fragments
    int m0 = blockIdx.x * 64;
    int kb = blockIdx.y;            // K-slice of 2048
    int kg = kb >> 1;               // which 4096-block (i*64+j space)
    int ihalf = (kb & 1) * 32;      // which half of the i range
    int tid = threadIdx.x;
    int lane = tid & 63, w = tid >> 6;
    int tt = lane >> 4, r16 = lane & 15;
    int wm = (w & 1) * 32, wn = (w >> 1) * 64;

    // zt tile: 64 rows x 64 cols fp32, swizzled
    {
        int row = tid >> 2, c0 = (tid & 3) * 16;
        const ushort* src = zb + (size_t)(m0 + row) * 1536 + 768 + kg * 64 + c0;
        uint4 v0 = *(const uint4*)src;
        uint4 v1 = *(const uint4*)(src + 8);
        uint uu[8] = {v0.x, v0.y, v0.z, v0.w, v1.x, v1.y, v1.z, v1.w};
        char* dst = (char*)zts_f + row * 256;
        int sw = (row & 7) << 4;
#pragma unroll
        for (int s = 0; s < 4; s++) {
            float4 fv;
            fv.x = __uint_as_float(uu[2 * s] << 16);
            fv.y = __uint_as_float(uu[2 * s] & 0xFFFF0000u);
            fv.z = __uint_as_float(uu[2 * s + 1] << 16);
            fv.w = __uint_as_float(uu[2 * s + 1] & 0xFFFF0000u);
            *(float4*)(dst + ((c0 * 4 + s * 16) ^ sw)) = fv;
        }
    }
    // zh tile: 64 rows x 32 cols fp32, stride 33
    {
        int row = tid >> 2, c0 = (tid & 3) * 8;
        const ushort* src = zb + (size_t)(m0 + row) * 1536 + kg * 64 + ihalf + c0;
        uint4 v = *(const uint4*)src;
        uint uu[4] = {v.x, v.y, v.z, v.w};
        float* dst = zhs_f + row * 33 + c0;
#pragma unroll
        for (int s = 0; s < 4; s++) {
            dst[2 * s]     = __uint_as_float(uu[s] << 16);
            dst[2 * s + 1] = __uint_as_float(uu[s] & 0xFFFF0000u);
        }
    }

    f32x4 acc[2][4];
    f32x4 zero = {0.f, 0.f, 0.f, 0.f};
#pragma unroll
    for (int t = 0; t < 2; t++)
#pragma unroll
        for (int n = 0; n < 4; n++) acc[t][n] = zero;

    const char* bbase = (const char*)bpack + (size_t)kb * 2048 * 256;
    for (int g = 0; g < 16; g++) {
        __syncthreads();
        const char* sb = bbase + (size_t)g * 32768;
#pragma unroll
        for (int q = 0; q < 8; q++) {
            int off = (q * 4 + w) * 1024;
            __builtin_amdgcn_global_load_lds(
                (const __attribute__((address_space(1))) void*)(sb + off + lane * 16),
                (__attribute__((address_space(3))) void*)((char*)Bls + off),
                16, 0, 0);
        }
        __syncthreads();
#pragma unroll
        for (int ks = 0; ks < 4; ks++) {
            int s = g * 4 + ks;
            int il = s >> 1;            // i within this slice's half
            int j0 = (s & 1) * 32;      // j chunk base
            bf16x8 af[2];
#pragma unroll
            for (int t = 0; t < 2; t++) {
                int row = wm + t * 16 + r16;
                float zhf = zhs_f[row * 33 + il];
                const char* zbase = (const char*)zts_f + row * 256;
                int sw = (row & 7) << 4;
                int b0 = (j0 + tt * 8) * 4;
                f32x4 zlo = *(const f32x4*)(zbase + (b0 ^ sw));
                f32x4 zhi = *(const f32x4*)(zbase + ((b0 + 16) ^ sw));
                float p0 = zlo[0] * zhf, p1 = zlo[1] * zhf;
                float p2 = zlo[2] * zhf, p3 = zlo[3] * zhf;
                float p4 = zhi[0] * zhf, p5 = zhi[1] * zhf;
                float p6 = zhi[2] * zhf, p7 = zhi[3] * zhf;
                union { bf16x8 v; uint u[4]; } a;
                asm("v_cvt_pk_bf16_f32 %0, %1, %2" : "=v"(a.u[0]) : "v"(p0), "v"(p1));
                asm("v_cvt_pk_bf16_f32 %0, %1, %2" : "=v"(a.u[1]) : "v"(p2), "v"(p3));
                asm("v_cvt_pk_bf16_f32 %0, %1, %2" : "=v"(a.u[2]) : "v"(p4), "v"(p5));
                asm("v_cvt_pk_bf16_f32 %0, %1, %2" : "=v"(a.u[3]) : "v"(p6), "v"(p7));
                af[t] = a.v;
            }
#pragma unroll
            for (int n = 0; n < 4; n++) {
                bf16x8 bf = *(const bf16x8*)&Bls[(size_t)((ks * 4 + tt) * NCP + wn + n * 16 + r16) * 8];
                acc[0][n] = __builtin_amdgcn_mfma_f32_16x16x32_bf16(af[0], bf, acc[0][n], 0, 0, 0);
                acc[1][n] = __builtin_amdgcn_mfma_f32_16x16x32_bf16(af[1], bf, acc[1][n], 0, 0, 0);
            }
        }
    }
    int rbase = (lane >> 4) * 4;
#pragma unroll
    for (int t = 0; t < 2; t++)
#pragma unroll
        for (int n = 0; n < 4; n++) {
            int c = wn + n * 16 + r16;
            if (c < NCLS) {
                int row = m0 + wm + t * 16 + rbase;
#pragma unroll
                for (int r = 0; r < 4; r++)
                    atomicAdd(&out[(size_t)(row + r) * NCLS + c], acc[t][n][r]);
            }
        }
}

// ---------------------------------------------------------------------------
extern "C" void kernel_launch(void* const* d_in, const int* in_sizes, int n_in,
                              void* d_out, int out_size, void* d_ws, size_t ws_size,
                              hipStream_t stream) {
    const float* seq  = (const float*)d_in[0];
    const float* attn = (const float*)d_in[1];
    const int*   ms   = (const int*)d_in[2];
    const int*   cs   = (const int*)d_in[3];
    const float* Wh   = (const float*)d_in[4];
    const float* bh   = (const float*)d_in[5];
    const float* Wt   = (const float*)d_in[6];
    const float* bt   = (const float*)d_in[7];
    const float* Wp   = (const float*)d_in[8];
    const float* Wc   = (const float*)d_in[9];
    const float* bc   = (const float*)d_in[10];
    float* out = (float*)d_out;

    // Workspace layout (no overlays; ~38 MB total).
    float* w     = (float*)d_ws;
    float* e_att = w;                          //   589,824 f
    float* eemb  = e_att + 589824;             //    36,864 f
    float* hsW   = eemb + 36864;               //    36,864 f
    float* tsW   = hsW + 36864;                //    36,864 f
    ushort* seqThi = (ushort*)(tsW + 36864);   // 1,572,864 us  [b][d][l]
    ushort* seqTlo = seqThi + 1572864;         // 1,572,864 us
    ushort* W2hi   = seqTlo + 1572864;         // 1,179,648 us  [n][k]
    ushort* W2lo   = W2hi + 1179648;           // 1,179,648 us
    ushort* hthi   = W2lo + 1179648;           // 1,179,648 us  [m][l]
    ushort* htlo   = hthi + 1179648;           // 1,179,648 us
    ushort* rshi   = htlo + 1179648;           //   884,736 us  [m][d]
    ushort* rslo   = rshi + 884736;            //   884,736 us
    ushort* zb     = rslo + 884736;            // 1,769,472 us  [m][n]
    ushort* wcpack = zb + 1769472;             //    86,016 us
    ushort* bpack  = wcpack + 86016;           // 6,291,456 us

    k_front<<<1295, 256, 0, stream>>>(attn, seq, ms, cs, Wc, Wh, Wt, bc,
                                      e_att, eemb, wcpack, seqThi, seqTlo, W2hi, W2lo, out);
    k_htwf<<<1920, 256, 0, stream>>>(e_att, Wp, wcpack, hthi, htlo, bpack);
    k_mid<<<2736, 128, 0, stream>>>(seqThi, seqTlo, hthi, htlo, eemb, Wh, Wt,
                                    rshi, rslo, hsW, tsW);
    k_rsw<<<dim3(18, 24), 256, 0, stream>>>(rshi, rslo, W2hi, W2lo, hsW, tsW, bh, bt, zb);
    k_logits<<<dim3(18, 24), 256, 0, stream>>>(zb, bpack, out);
}

// Round 5
// 394.171 us; speedup vs baseline: 1.1372x; 1.1372x over previous
//
#include <hip/hip_runtime.h>
#include <math.h>

// Problem constants
#define BB   2
#define LL   1024
#define HH   768
#define NHH  12
#define NEE  24
#define MMM  3
#define NCC  2
#define CWW  8
#define BLK  64
#define NCLS 97
#define HB   49152       // HH*BLK
#define NCP  128         // padded class dim for Wf
#define NCT  7           // class tiles computed (112 >= 97)
#define NEF  1152        // BB*NEE*NEE

typedef unsigned int uint;
typedef unsigned short ushort;
typedef __attribute__((ext_vector_type(8))) short bf16x8;
typedef __attribute__((ext_vector_type(4))) float f32x4;

// round-to-nearest-even fp32 -> bf16
__device__ __forceinline__ ushort f2bf(float f) {
    uint u = __float_as_uint(f);
    u += 0x7fffu + ((u >> 16) & 1u);
    return (ushort)(u >> 16);
}

// split fp32 into hi+lo bf16 (hi RNE, lo = RNE(f - hi)): ~16-bit mantissa total
__device__ __forceinline__ void splitbf(float f, ushort& h, ushort& l) {
    h = f2bf(f);
    float hf = __uint_as_float((uint)h << 16);
    l = f2bf(f - hf);
}

#define GLDS(srcp, dstoff) \
    __builtin_amdgcn_global_load_lds( \
        (const __attribute__((address_space(1))) void*)(srcp), \
        (__attribute__((address_space(3))) void*)(dstoff), 16, 0, 0)

// ---------------------------------------------------------------------------
// K0 k_front: all input-only preprocessing in one launch. (unchanged)
__global__ void k_front(const float* __restrict__ att_in, const float* __restrict__ seq,
                        const int* __restrict__ ms, const int* __restrict__ cs,
                        const float* __restrict__ Wc, const float* __restrict__ Wh,
                        const float* __restrict__ Wt, const float* __restrict__ bc,
                        float* __restrict__ e_att, float* __restrict__ e_emb,
                        ushort* __restrict__ wcpack,
                        ushort* __restrict__ seqThi, ushort* __restrict__ seqTlo,
                        ushort* __restrict__ W2hi, ushort* __restrict__ W2lo,
                        float* __restrict__ out) {
    __shared__ float sm[13328];     // head: es[12*1024]+gs[1024]+red[16]; transpose: 64x65
    int bid = blockIdx.x;
    int tid = threadIdx.x;
    if (bid < 42) {
        int t = bid * 256 + tid;
        if (t >= 24 * NCT * 64) return;
        int kc = t / (NCT * 64);
        int r = t % (NCT * 64);
        int ct = r >> 6;
        int lane = r & 63;
        int c = ct * 16 + (lane & 15);
        int k0 = kc * 32 + (lane >> 4) * 8;
        uint u[4] = {0u, 0u, 0u, 0u};
        if (c < NCLS) {
            const float* src = Wc + (size_t)c * HH + k0;
            float4 f0 = *(const float4*)src;
            float4 f1 = *(const float4*)(src + 4);
            u[0] = (uint)f2bf(f0.x) | ((uint)f2bf(f0.y) << 16);
            u[1] = (uint)f2bf(f0.z) | ((uint)f2bf(f0.w) << 16);
            u[2] = (uint)f2bf(f1.x) | ((uint)f2bf(f1.y) << 16);
            u[3] = (uint)f2bf(f1.z) | ((uint)f2bf(f1.w) << 16);
        }
        *(uint4*)(wcpack + (size_t)t * 8) = make_uint4(u[0], u[1], u[2], u[3]);
    } else if (bid < 479) {
        int i = (bid - 42) * 256 + tid;
        if (i < NEF * NCLS) out[i] = bc[i % NCLS];
    } else if (bid < 527) {
        // head: per (b,e)
        float* es = sm;                // 12*1024
        float* gs = sm + 12288;        // 1024
        float* red = sm + 13312;       // 4
        int be = bid - 479;
        int b = be / NEE;
        int base = be * MMM;
        int p0 = ms[base + 0] + 1, p1 = ms[base + 1] + 1, p2 = ms[base + 2] + 1;
        float* eo = e_att + (size_t)be * NHH * LL;
        for (int h = 0; h < NHH; h++) {
            const float* basep = att_in + (size_t)(b * NHH + h) * LL * LL;
#pragma unroll
            for (int i = 0; i < 4; i++) {
                int l = tid + i * 256;
                float v = (basep[(size_t)p0 * LL + l] + basep[(size_t)p1 * LL + l] +
                           basep[(size_t)p2 * LL + l]) * (1.f / 3.f);
                es[h * LL + l] = v;
                eo[h * LL + l] = v;
            }
        }
        __syncthreads();
        float part = 0.f;
#pragma unroll
        for (int i = 0; i < 4; i++) {
            int l = tid + i * 256;
            float a = 0.f;
#pragma unroll
            for (int h = 0; h < NHH; h++) a += es[h * LL + l];
            gs[l] = a;
            part += a;
        }
        for (int off = 32; off; off >>= 1) part += __shfl_down(part, off, 64);
        if ((tid & 63) == 0) red[tid >> 6] = part;
        __syncthreads();
        float inv = 1.f / (red[0] + red[1] + red[2] + red[3]);
#pragma unroll
        for (int i = 0; i < 4; i++) gs[tid + i * 256] *= inv;
        __syncthreads();
        int c0 = cs[be * NCC + 0], c1 = cs[be * NCC + 1];
        for (int d = tid; d < HH; d += 256) {
            float v0 = seq[((size_t)b * LL + p0) * HH + d];
            float v1 = seq[((size_t)b * LL + p1) * HH + d];
            float v2 = seq[((size_t)b * LL + p2) * HH + d];
            float s0 = 0.f, s1 = 0.f;
#pragma unroll
            for (int w = 0; w < CWW; w++) {
                s0 += gs[c0 + w] * seq[((size_t)b * LL + c0 + w) * HH + d];
                s1 += gs[c1 + w] * seq[((size_t)b * LL + c1 + w) * HH + d];
            }
            float mx = fmaxf(fmaxf(fmaxf(v0, v1), fmaxf(v2, s0)), s1);
            float se = expf(v0 - mx) + expf(v1 - mx) + expf(v2 - mx) + expf(s0 - mx) + expf(s1 - mx);
            e_emb[(size_t)be * HH + d] = logf(se) + mx;
        }
    } else if (bid < 911) {
        // seq^T split-transpose: 64(l) x 64(d) tiles
        float (*tile)[65] = (float(*)[65])sm;
        int idx = bid - 527;
        int b = idx / 192;
        int rem = idx % 192;
        int l0 = (rem / 12) * 64;
        int d0 = (rem % 12) * 64;
        int dq = tid >> 6, dl = tid & 63;
#pragma unroll 4
        for (int r = 0; r < 16; r++) {
            int l_in = r * 4 + dq;
            tile[l_in][dl] = seq[((size_t)(b * LL + l0 + l_in)) * HH + d0 + dl];
        }
        __syncthreads();
#pragma unroll 4
        for (int r = 0; r < 16; r++) {
            int d_out = r * 4 + dq;
            float v = tile[dl][d_out];
            ushort h, l;
            splitbf(v, h, l);
            size_t o = ((size_t)(b * HH + d0 + d_out)) * LL + l0 + dl;
            seqThi[o] = h;
            seqTlo[o] = l;
        }
    } else {
        // W2 split pack: W2[n][k] = (n<768 ? Wh : Wt)[n%768][768+k]
        int idx = bid - 911;
#pragma unroll
        for (int rr = 0; rr < 4; rr++) {
            int n = idx * 4 + rr;
            const float* src = (n < HH) ? (Wh + (size_t)n * (2 * HH) + HH)
                                        : (Wt + (size_t)(n - HH) * (2 * HH) + HH);
            for (int k = tid; k < HH; k += 256) {
                ushort h, l;
                splitbf(src[k], h, l);
                W2hi[(size_t)n * HH + k] = h;
                W2lo[(size_t)n * HH + k] = l;
            }
        }
    }
}

// ---------------------------------------------------------------------------
// K1 k_htwf:
//   [0,768):     wf — bf16 MFMA GEMM for Wf; Wp staged via DOUBLE-BUFFERED
//                global_load_lds (1 barrier per kc, prefetch overlaps MFMA)
//   [768,1920):  ht — relu+normalize, emitted pre-split as hthi/htlo
__global__ void k_htwf(const float* __restrict__ e_att, const float* __restrict__ Wp,
                       const ushort* __restrict__ wcpack, ushort* __restrict__ hthi,
                       ushort* __restrict__ htlo, ushort* __restrict__ bpack) {
    __shared__ float smem[4096];    // wf: 2 x 8KB Wp tile; ht: hts[1024]+red[4]
    int bid = blockIdx.x;
    int tid = threadIdx.x;
    int lane = tid & 63, w = tid >> 6;
    if (bid < 768) {
        int r16 = lane & 15, tt = lane >> 4;
        int n0 = bid * 64;
        const uint4* wb = (const uint4*)wcpack;

        auto stage = [&](int buf, int kc) {
#pragma unroll
            for (int q = 0; q < 2; q++) {
                int slot = q * 256 + w * 64;          // wave-uniform 16B-slot base
                int idx = slot + lane;
                int srow = idx >> 4;
                int scol = (idx & 15) * 4;
                GLDS(Wp + (size_t)(kc * 32 + srow) * HB + n0 + scol,
                     (char*)smem + buf * 8192 + slot * 16);
            }
        };

        f32x4 acc[NCT];
        f32x4 zero = {0.f, 0.f, 0.f, 0.f};
#pragma unroll
        for (int ct = 0; ct < NCT; ct++) acc[ct] = zero;

        stage(0, 0);
        __syncthreads();
        for (int kc = 0; kc < 24; kc++) {
            int buf = kc & 1;
            if (kc < 23) stage(buf ^ 1, kc + 1);
            const float* sf = smem + buf * 2048;
            float f[8];
#pragma unroll
            for (int j = 0; j < 8; j++) f[j] = sf[(tt * 8 + j) * 64 + w * 16 + r16];
            union { bf16x8 v; uint u[4]; } a;
#pragma unroll
            for (int q = 0; q < 4; q++)
                a.u[q] = (__float_as_uint(f[2 * q]) >> 16) |
                         (__float_as_uint(f[2 * q + 1]) & 0xFFFF0000u);  // truncate pair
#pragma unroll
            for (int ct = 0; ct < NCT; ct++) {
                union { uint4 q; bf16x8 v; } b;
                b.q = wb[(size_t)(kc * NCT + ct) * 64 + lane];
                acc[ct] = __builtin_amdgcn_mfma_f32_16x16x32_bf16(a.v, b.v, acc[ct], 0, 0, 0);
            }
            __syncthreads();
        }
#pragma unroll
        for (int ct = 0; ct < NCT; ct++) {
            int c = ct * 16 + r16;
#pragma unroll
            for (int r = 0; r < 4; r++) {
                int n = n0 + w * 16 + tt * 4 + r;
                bpack[((size_t)(n >> 3) * NCP + c) * 8 + (n & 7)] = f2bf(acc[ct][r]);
            }
        }
    } else {
        float* hts = smem;
        float* red = smem + 1024;
        int blk = bid - 768;            // ((b*NEE+e)*NEE+f)
        int f = blk % NEE;
        int e = (blk / NEE) % NEE;
        int b = blk / (NEE * NEE);
        const float* ea = e_att + (size_t)(b * NEE + e) * NHH * LL;
        const float* fa = e_att + (size_t)(b * NEE + f) * NHH * LL;
        float lsum = 0.f;
        for (int l = tid; l < LL; l += 256) {
            float s = 0.f;
            for (int h = 0; h < NHH; h++) s += ea[h * LL + l] * fa[h * LL + l];
            s = fmaxf(s, 0.f);
            hts[l] = s;
            lsum += s;
        }
        for (int off = 32; off; off >>= 1) lsum += __shfl_down(lsum, off, 64);
        if ((tid & 63) == 0) red[tid >> 6] = lsum;
        __syncthreads();
        float inv = 1.f / (red[0] + red[1] + red[2] + red[3] + 1e-10f);
        for (int l = tid; l < LL; l += 256) {
            ushort h, lo;
            splitbf(hts[l] * inv, h, lo);
            hthi[(size_t)blk * LL + l] = h;
            htlo[(size_t)blk * LL + l] = lo;
        }
    }
}

// ---------------------------------------------------------------------------
// K2 k_mid (256 threads):
//   [0,432):      rs GEMM (split-bf16 MFMA), M-tile 64 x N-tile 32, K=1024 in
//                 32 steps; A/B double-buffer-staged in LDS via global_load_lds
//                 (was: 10 direct L2 loads per kc on the critical path).
//   [432,1584):   hsW/tsW (e_emb @ first-768-cols of Wh/Wt)
__global__ void k_mid(const ushort* __restrict__ seqThi, const ushort* __restrict__ seqTlo,
                      const ushort* __restrict__ hthi, const ushort* __restrict__ htlo,
                      const float* __restrict__ e_emb, const float* __restrict__ Wh,
                      const float* __restrict__ Wt, ushort* __restrict__ rshi,
                      ushort* __restrict__ rslo, float* __restrict__ hsW,
                      float* __restrict__ tsW) {
    // GEMM: 2 bufs x 12KB: Ah[64][32] Al[64][32] Bh[32][32] Bl[32][32] (ushort)
    __shared__ ushort ldsu[12288];      // 24 KB
    int bid = blockIdx.x;
    int tid = threadIdx.x;
    int lane = tid & 63, w = tid >> 6;
    if (bid < 432) {
        int b = bid / 216;
        int rem = bid % 216;
        int m0 = (rem / 24) * 64;           // 9 m-tiles
        int n0 = (rem % 24) * 32;           // 24 n-tiles
        int bm = b * 576 + m0;
        int bn = b * HH + n0;
        int r16 = lane & 15, tt = lane >> 4;

        auto stage = [&](int buf, int kc) {
            int row = tid >> 2;
            int ko = kc * 32 + (tid & 3) * 8;
#pragma unroll
            for (int q = 0; q < 2; q++) {
                const ushort* src = (q ? htlo : hthi) + (size_t)(bm + row) * LL + ko;
                GLDS(src, (char*)ldsu + buf * 12288 + q * 4096 + w * 1024);
            }
            if (w < 2) {
                const ushort* src = seqThi + (size_t)(bn + row) * LL + ko;
                GLDS(src, (char*)ldsu + buf * 12288 + 8192 + w * 1024);
            } else {
                int row2 = (tid - 128) >> 2;
                const ushort* src = seqTlo + (size_t)(bn + row2) * LL + ko;
                GLDS(src, (char*)ldsu + buf * 12288 + 10240 + (w - 2) * 1024);
            }
        };

        f32x4 acc[2];
        f32x4 zero = {0.f, 0.f, 0.f, 0.f};
        acc[0] = zero; acc[1] = zero;

        stage(0, 0);
        __syncthreads();
        for (int kc = 0; kc < 32; kc++) {
            int buf = kc & 1;
            if (kc < 31) stage(buf ^ 1, kc + 1);
            const ushort* Lb = ldsu + buf * 6144;
            bf16x8 ah = *(const bf16x8*)&Lb[(w * 16 + r16) * 32 + tt * 8];
            bf16x8 al = *(const bf16x8*)&Lb[2048 + (w * 16 + r16) * 32 + tt * 8];
#pragma unroll
            for (int nt = 0; nt < 2; nt++) {
                bf16x8 bh = *(const bf16x8*)&Lb[4096 + (nt * 16 + r16) * 32 + tt * 8];
                bf16x8 bl = *(const bf16x8*)&Lb[5120 + (nt * 16 + r16) * 32 + tt * 8];
                acc[nt] = __builtin_amdgcn_mfma_f32_16x16x32_bf16(ah, bh, acc[nt], 0, 0, 0);
                acc[nt] = __builtin_amdgcn_mfma_f32_16x16x32_bf16(ah, bl, acc[nt], 0, 0, 0);
                acc[nt] = __builtin_amdgcn_mfma_f32_16x16x32_bf16(al, bh, acc[nt], 0, 0, 0);
            }
            __syncthreads();
        }
#pragma unroll
        for (int nt = 0; nt < 2; nt++) {
#pragma unroll
            for (int r = 0; r < 4; r++) {
                int m = bm + w * 16 + tt * 4 + r;
                int d = n0 + nt * 16 + r16;
                ushort h, l;
                splitbf(acc[nt][r], h, l);
                rshi[(size_t)m * HH + d] = h;
                rslo[(size_t)m * HH + d] = l;
            }
        }
    } else {
        float* xs = (float*)ldsu;
        int r = bid - 432;                // 0..1151
        int m2 = r % 48;
        int which = (r / 48) & 1;
        int chunk = r / 96;               // 0..11 (64 d's each)
        const float* Wm = which ? Wt : Wh;
        float* outp = which ? tsW : hsW;
        const float* x = e_emb + (size_t)m2 * HH;
        for (int j = tid; j < HH; j += 256) xs[j] = x[j];
        __syncthreads();
        int d0 = chunk * 64 + w * 16;
#pragma unroll 4
        for (int i = 0; i < 16; i++) {
            int d = d0 + i;
            const float* wr = Wm + (size_t)d * (2 * HH);
            float s = 0.f;
#pragma unroll
            for (int jj = 0; jj < 12; jj++) s += xs[lane + jj * 64] * wr[lane + jj * 64];
            for (int off = 32; off; off >>= 1) s += __shfl_down(s, off, 64);
            if (lane == 0) outp[(size_t)m2 * HH + d] = s;
        }
    }
}

// ---------------------------------------------------------------------------
// K3 k_rsw: split-bf16 MFMA GEMM + tanh epilogue -> zb. M=1152,N=1536,K=768.
// A and B (hi+lo) staged in LDS via double-buffered global_load_lds; B shared
// by all 4 waves (was 4x redundant L2 fetch, 10 latency-bound loads per kc).
__global__ void k_rsw(const ushort* __restrict__ rshi, const ushort* __restrict__ rslo,
                      const ushort* __restrict__ W2hi, const ushort* __restrict__ W2lo,
                      const float* __restrict__ hsW, const float* __restrict__ tsW,
                      const float* __restrict__ bh, const float* __restrict__ bt,
                      ushort* __restrict__ zb) {
    // 2 bufs x 16KB: Ah[64][32] Al[64][32] Bh[64][32] Bl[64][32] (ushort)
    __shared__ ushort lds[16384];       // 32 KB
    int m0 = blockIdx.x * 64, n0 = blockIdx.y * 64;
    int tid = threadIdx.x;
    int lane = tid & 63, w = tid >> 6;
    int r16 = lane & 15, tt = lane >> 4;

    auto stage = [&](int buf, int kc) {
        int row = tid >> 2;
        int ko = kc * 32 + (tid & 3) * 8;
        const ushort* s0 = rshi + (size_t)(m0 + row) * HH + ko;
        const ushort* s1 = rslo + (size_t)(m0 + row) * HH + ko;
        const ushort* s2 = W2hi + (size_t)(n0 + row) * HH + ko;
        const ushort* s3 = W2lo + (size_t)(n0 + row) * HH + ko;
        char* base = (char*)lds + buf * 16384 + w * 1024;
        GLDS(s0, base);
        GLDS(s1, base + 4096);
        GLDS(s2, base + 8192);
        GLDS(s3, base + 12288);
    };

    f32x4 acc[4];
    f32x4 zero = {0.f, 0.f, 0.f, 0.f};
#pragma unroll
    for (int nt = 0; nt < 4; nt++) acc[nt] = zero;

    stage(0, 0);
    __syncthreads();
    for (int kc = 0; kc < 24; kc++) {
        int buf = kc & 1;
        if (kc < 23) stage(buf ^ 1, kc + 1);
        const ushort* Lb = lds + buf * 8192;
        bf16x8 ah = *(const bf16x8*)&Lb[(w * 16 + r16) * 32 + tt * 8];
        bf16x8 al = *(const bf16x8*)&Lb[2048 + (w * 16 + r16) * 32 + tt * 8];
#pragma unroll
        for (int nt = 0; nt < 4; nt++) {
            bf16x8 vbh = *(const bf16x8*)&Lb[4096 + (nt * 16 + r16) * 32 + tt * 8];
            bf16x8 vbl = *(const bf16x8*)&Lb[6144 + (nt * 16 + r16) * 32 + tt * 8];
            acc[nt] = __builtin_amdgcn_mfma_f32_16x16x32_bf16(ah, vbh, acc[nt], 0, 0, 0);
            acc[nt] = __builtin_amdgcn_mfma_f32_16x16x32_bf16(ah, vbl, acc[nt], 0, 0, 0);
            acc[nt] = __builtin_amdgcn_mfma_f32_16x16x32_bf16(al, vbh, acc[nt], 0, 0, 0);
        }
        __syncthreads();
    }
    bool isHead = (n0 < HH);
    const float* bias = isHead ? bh : bt;
#pragma unroll
    for (int nt = 0; nt < 4; nt++) {
#pragma unroll
        for (int r = 0; r < 4; r++) {
            int m = m0 + w * 16 + tt * 4 + r;
            int n = n0 + nt * 16 + r16;
            int bb = m / 576;
            int rr = m % 576;
            int e = rr / NEE, f = rr % NEE;
            int d = isHead ? n : (n - HH);
            const float* addrow = isHead ? (hsW + (size_t)(bb * NEE + e) * HH)
                                         : (tsW + (size_t)(bb * NEE + f) * HH);
            float v = tanhf(acc[nt][r] + addrow[d] + bias[d]);
            zb[(size_t)m * (2 * HH) + n] = f2bf(v);
        }
    }
}

// ---------------------------------------------------------------------------
// K4 k_logits: MFMA logits (unchanged from round 4).
__global__ __launch_bounds__(256, 2) void k_logits(const ushort* __restrict__ zb,
                                                   const ushort* __restrict__ bpack,
                                                   float* __restrict__ out) {
    __shared__ float zhs_f[64 * 33];    // 8.25KB
    __shared__ float zts_f[64 * 64];    // 16KB, 16B slots XORed by ((row&7)<<4)
    __shared__ ushort Bls[16384];       // 32KB: one K=128 stage of B-fragments
    int m0 = blockIdx.x * 64;
    int kb = blockIdx.y;            // K-slice of 2048
    int kg = kb >> 1;               // which 4096-block (i*64+j space)
    int ihalf = (kb & 1) * 32;      // which half of the i range
    int tid = threadIdx.x;
    int lane = tid & 63, w = tid >> 6;
    int tt = lane >> 4, r16 = lane & 15;
    int wm = (w & 1) * 32, wn = (w >> 1) * 64;

    {
        int row = tid >> 2, c0 = (tid & 3) * 16;
        const ushort* src = zb + (size_t)(m0 + row) * 1536 + 768 + kg * 64 + c0;
        uint4 v0 = *(const uint4*)src;
        uint4 v1 = *(const uint4*)(src + 8);
        uint uu[8] = {v0.x, v0.y, v0.z, v0.w, v1.x, v1.y, v1.z, v1.w};
        char* dst = (char*)zts_f + row * 256;
        int sw = (row & 7) << 4;
#pragma unroll
        for (int s = 0; s < 4; s++) {
            float4 fv;
            fv.x = __uint_as_float(uu[2 * s] << 16);
            fv.y = __uint_as_float(uu[2 * s] & 0xFFFF0000u);
            fv.z = __uint_as_float(uu[2 * s + 1] << 16);
            fv.w = __uint_as_float(uu[2 * s + 1] & 0xFFFF0000u);
            *(float4*)(dst + ((c0 * 4 + s * 16) ^ sw)) = fv;
        }
    }
    {
        int row = tid >> 2, c0 = (tid & 3) * 8;
        const ushort* src = zb + (size_t)(m0 + row) * 1536 + kg * 64 + ihalf + c0;
        uint4 v = *(const uint4*)src;
        uint uu[4] = {v.x, v.y, v.z, v.w};
        float* dst = zhs_f + row * 33 + c0;
#pragma unroll
        for (int s = 0; s < 4; s++) {
            dst[2 * s]     = __uint_as_float(uu[s] << 16);
            dst[2 * s + 1] = __uint_as_float(uu[s] & 0xFFFF0000u);
        }
    }

    f32x4 acc[2][4];
    f32x4 zero = {0.f, 0.f, 0.f, 0.f};
#pragma unroll
    for (int t = 0; t < 2; t++)
#pragma unroll
        for (int n = 0; n < 4; n++) acc[t][n] = zero;

    const char* bbase = (const char*)bpack + (size_t)kb * 2048 * 256;
    for (int g = 0; g < 16; g++) {
        __syncthreads();
        const char* sb = bbase + (size_t)g * 32768;
#pragma unroll
        for (int q = 0; q < 8; q++) {
            int off = (q * 4 + w) * 1024;
            __builtin_amdgcn_global_load_lds(
                (const __attribute__((address_space(1))) void*)(sb + off + lane * 16),
                (__attribute__((address_space(3))) void*)((char*)Bls + off),
                16, 0, 0);
        }
        __syncthreads();
#pragma unroll
        for (int ks = 0; ks < 4; ks++) {
            int s = g * 4 + ks;
            int il = s >> 1;            // i within this slice's half
            int j0 = (s & 1) * 32;      // j chunk base
            bf16x8 af[2];
#pragma unroll
            for (int t = 0; t < 2; t++) {
                int row = wm + t * 16 + r16;
                float zhf = zhs_f[row * 33 + il];
                const char* zbase = (const char*)zts_f + row * 256;
                int sw = (row & 7) << 4;
                int b0 = (j0 + tt * 8) * 4;
                f32x4 zlo = *(const f32x4*)(zbase + (b0 ^ sw));
                f32x4 zhi = *(const f32x4*)(zbase + ((b0 + 16) ^ sw));
                float p0 = zlo[0] * zhf, p1 = zlo[1] * zhf;
                float p2 = zlo[2] * zhf, p3 = zlo[3] * zhf;
                float p4 = zhi[0] * zhf, p5 = zhi[1] * zhf;
                float p6 = zhi[2] * zhf, p7 = zhi[3] * zhf;
                union { bf16x8 v; uint u[4]; } a;
                asm("v_cvt_pk_bf16_f32 %0, %1, %2" : "=v"(a.u[0]) : "v"(p0), "v"(p1));
                asm("v_cvt_pk_bf16_f32 %0, %1, %2" : "=v"(a.u[1]) : "v"(p2), "v"(p3));
                asm("v_cvt_pk_bf16_f32 %0, %1, %2" : "=v"(a.u[2]) : "v"(p4), "v"(p5));
                asm("v_cvt_pk_bf16_f32 %0, %1, %2" : "=v"(a.u[3]) : "v"(p6), "v"(p7));
                af[t] = a.v;
            }
#pragma unroll
            for (int n = 0; n < 4; n++) {
                bf16x8 bf = *(const bf16x8*)&Bls[(size_t)((ks * 4 + tt) * NCP + wn + n * 16 + r16) * 8];
                acc[0][n] = __builtin_amdgcn_mfma_f32_16x16x32_bf16(af[0], bf, acc[0][n], 0, 0, 0);
                acc[1][n] = __builtin_amdgcn_mfma_f32_16x16x32_bf16(af[1], bf, acc[1][n], 0, 0, 0);
            }
        }
    }
    int rbase = (lane >> 4) * 4;
#pragma unroll
    for (int t = 0; t < 2; t++)
#pragma unroll
        for (int n = 0; n < 4; n++) {
            int c = wn + n * 16 + r16;
            if (c < NCLS) {
                int row = m0 + wm + t * 16 + rbase;
#pragma unroll
                for (int r = 0; r < 4; r++)
                    atomicAdd(&out[(size_t)(row + r) * NCLS + c], acc[t][n][r]);
            }
        }
}

// ---------------------------------------------------------------------------
extern "C" void kernel_launch(void* const* d_in, const int* in_sizes, int n_in,
                              void* d_out, int out_size, void* d_ws, size_t ws_size,
                              hipStream_t stream) {
    const float* seq  = (const float*)d_in[0];
    const float* attn = (const float*)d_in[1];
    const int*   ms   = (const int*)d_in[2];
    const int*   cs   = (const int*)d_in[3];
    const float* Wh   = (const float*)d_in[4];
    const float* bh   = (const float*)d_in[5];
    const float* Wt   = (const float*)d_in[6];
    const float* bt   = (const float*)d_in[7];
    const float* Wp   = (const float*)d_in[8];
    const float* Wc   = (const float*)d_in[9];
    const float* bc   = (const float*)d_in[10];
    float* out = (float*)d_out;

    // Workspace layout (no overlays; ~38 MB total).
    float* w     = (float*)d_ws;
    float* e_att = w;                          //   589,824 f
    float* eemb  = e_att + 589824;             //    36,864 f
    float* hsW   = eemb + 36864;               //    36,864 f
    float* tsW   = hsW + 36864;                //    36,864 f
    ushort* seqThi = (ushort*)(tsW + 36864);   // 1,572,864 us  [b][d][l]
    ushort* seqTlo = seqThi + 1572864;         // 1,572,864 us
    ushort* W2hi   = seqTlo + 1572864;         // 1,179,648 us  [n][k]
    ushort* W2lo   = W2hi + 1179648;           // 1,179,648 us
    ushort* hthi   = W2lo + 1179648;           // 1,179,648 us  [m][l]
    ushort* htlo   = hthi + 1179648;           // 1,179,648 us
    ushort* rshi   = htlo + 1179648;           //   884,736 us  [m][d]
    ushort* rslo   = rshi + 884736;            //   884,736 us
    ushort* zb     = rslo + 884736;            // 1,769,472 us  [m][n]
    ushort* wcpack = zb + 1769472;             //    86,016 us
    ushort* bpack  = wcpack + 86016;           // 6,291,456 us

    k_front<<<1295, 256, 0, stream>>>(attn, seq, ms, cs, Wc, Wh, Wt, bc,
                                      e_att, eemb, wcpack, seqThi, seqTlo, W2hi, W2lo, out);
    k_htwf<<<1920, 256, 0, stream>>>(e_att, Wp, wcpack, hthi, htlo, bpack);
    k_mid<<<432 + 1152, 256, 0, stream>>>(seqThi, seqTlo, hthi, htlo, eemb, Wh, Wt,
                                          rshi, rslo, hsW, tsW);
    k_rsw<<<dim3(18, 24), 256, 0, stream>>>(rshi, rslo, W2hi, W2lo, hsW, tsW, bh, bt, zb);
    k_logits<<<dim3(18, 24), 256, 0, stream>>>(zb, bpack, out);
}